// Round 9
// baseline (3350.338 us; speedup 1.0000x reference)
//
#include <hip/hip_runtime.h>
#include <math.h>
#include <stdint.h>

#define BB 32
#define TT 1024
#define INF 256
#define HH 128
#define G4 512   // 4*H

typedef _Float16 half2_t __attribute__((ext_vector_type(2)));
typedef _Float16 f16x8 __attribute__((ext_vector_type(8)));
typedef float f32x4 __attribute__((ext_vector_type(4)));

__device__ __forceinline__ float fdot2f(half2_t a, half2_t b, float c) {
    return __builtin_amdgcn_fdot2(a, b, c, false);
}
__device__ __forceinline__ float rcpf(float x) {
    return __builtin_amdgcn_rcpf(x);
}
// workgroup barrier draining ONLY lgkmcnt — global loads/stores stay in flight
__device__ __forceinline__ void bar_lgkm() {
    asm volatile("s_waitcnt lgkmcnt(0)\n\ts_barrier" ::: "memory");
}

// =============== GEMM v8: f16 dot2, 128x128 tile; transposed epilogue ===============
// Row index m = t*32 + b (t-major). Output layout xproj[d][t][n][b32] so the
// MFMA lstm kernel can read x as coalesced float4 over 4 consecutive batches.
__global__ __launch_bounds__(256, 2) void gemm_inproj(
    const float* __restrict__ A,        // [32][1024][INF]  (b-major rows)
    const float* __restrict__ w_ih_l,   // 2 x 512 x INF  (this layer's slice)
    const float* __restrict__ b_ih_l,   // 2 x 512
    const float* __restrict__ b_hh_l,   // 2 x 512
    float* __restrict__ xproj)          // [2][1024][512][32]
{
    const int d  = blockIdx.z;
    const float* W = w_ih_l + (size_t)d * G4 * INF;
    float* C = xproj + (size_t)d * 1024 * 512 * 32;
    const int m0 = blockIdx.y * 128;    // t-major row base (multiple of 128)
    const int n0 = blockIdx.x * 128;
    const int tid = threadIdx.x;
    const int tx = tid & 15, ty = tid >> 4;

    __shared__ __align__(16) half2_t As2[16 * 128];   // 8 KB
    __shared__ __align__(16) half2_t Bs2[16 * 128];   // 8 KB

    float acc[8][8] = {};
    const int lr = tid >> 1;         // 0..127 : row for staging
    const int lk = (tid & 1) * 16;   // k offset for staging (16 floats/thread)

    const int mrow = m0 + lr;        // t-major index
    const size_t arow = ((size_t)(mrow & 31) * 1024 + (size_t)(mrow >> 5)) * INF;

    float4 ar4[4], br4[4];
#pragma unroll
    for (int i = 0; i < 4; ++i) {
        ar4[i] = *(const float4*)(A + arow + lk + 4 * i);
        br4[i] = *(const float4*)(W + (size_t)(n0 + lr) * INF + lk + 4 * i);
    }

    for (int k0 = 0; k0 < 256; k0 += 32) {
        __syncthreads();
#pragma unroll
        for (int i = 0; i < 4; ++i) {
            const int kp = (lk >> 1) + 2 * i;   // k-pair index
            As2[(kp + 0) * 128 + lr] = half2_t{(_Float16)ar4[i].x, (_Float16)ar4[i].y};
            As2[(kp + 1) * 128 + lr] = half2_t{(_Float16)ar4[i].z, (_Float16)ar4[i].w};
            Bs2[(kp + 0) * 128 + lr] = half2_t{(_Float16)br4[i].x, (_Float16)br4[i].y};
            Bs2[(kp + 1) * 128 + lr] = half2_t{(_Float16)br4[i].z, (_Float16)br4[i].w};
        }
        __syncthreads();
        if (k0 + 32 < 256) {
#pragma unroll
            for (int i = 0; i < 4; ++i) {
                ar4[i] = *(const float4*)(A + arow + k0 + 32 + lk + 4 * i);
                br4[i] = *(const float4*)(W + (size_t)(n0 + lr) * INF + k0 + 32 + lk + 4 * i);
            }
        }
#pragma unroll
        for (int kp = 0; kp < 16; ++kp) {
            half2_t av[8], bv[8];
            *(float4*)&av[0] = *(const float4*)&As2[kp * 128 + ty * 4];
            *(float4*)&av[4] = *(const float4*)&As2[kp * 128 + 64 + ty * 4];
            *(float4*)&bv[0] = *(const float4*)&Bs2[kp * 128 + tx * 4];
            *(float4*)&bv[4] = *(const float4*)&Bs2[kp * 128 + 64 + tx * 4];
#pragma unroll
            for (int i = 0; i < 8; ++i)
#pragma unroll
                for (int j = 0; j < 8; ++j)
                    acc[i][j] = fdot2f(av[i], bv[j], acc[i][j]);
        }
    }

    float bias[8];
#pragma unroll
    for (int j = 0; j < 8; ++j) {
        const int n = n0 + (j < 4 ? tx * 4 + j : 64 + tx * 4 + (j - 4));
        bias[j] = b_ih_l[d * G4 + n] + b_hh_l[d * G4 + n];
    }
#pragma unroll
    for (int q = 0; q < 2; ++q) {
        const int rbase = q * 64 + ty * 4;
        const int t = (m0 >> 5) + (rbase >> 5);
        const int b = rbase & 31;            // multiple of 4
#pragma unroll
        for (int j = 0; j < 8; ++j) {
            const int n = n0 + (j < 4 ? tx * 4 + j : 64 + tx * 4 + (j - 4));
            float4 v;
            v.x = acc[q * 4 + 0][j] + bias[j];
            v.y = acc[q * 4 + 1][j] + bias[j];
            v.z = acc[q * 4 + 2][j] + bias[j];
            v.w = acc[q * 4 + 3][j] + bias[j];
            *(float4*)(C + ((size_t)t * 512 + n) * 32 + b) = v;
        }
    }
}

// =============== LSTM recurrence v8: MFMA over 16 batched chains ===============
// Block = (direction d, batch-half hb): 16 chains. 8 waves; wave w owns
// N-tiles = gates i,f,g,o for j in [16w,16w+16).
// Per step: gates(16x512) = H(16x128) @ Whh^T via mfma_f32_16x16x32_f16
// (A-layout: batch=lane&15, k=j; C-layout: batch=(lane>>4)*4+reg, col=j)
// -> i,f,g,o land in matching reg positions; c/h update in-register.
// h round-trips through double-buffered padded LDS; one lgkm barrier/step.
__global__ __launch_bounds__(512, 1) void lstm_rec(
    const float* __restrict__ xproj,   // [2][1024][512][32]
    const float* __restrict__ w_hh_l,  // 2 x 512 x 128 (this layer's slice)
    float* __restrict__ out)           // B x T x 256  ([fwd|bwd] concat)
{
    const int d  = blockIdx.x >> 1;
    const int hb = blockIdx.x & 1;
    const int tid = threadIdx.x;
    const int w = tid >> 6;
    const int l = tid & 63;
    const int col = l & 15;
    const int qg = l >> 4;
    const int j = w * 16 + col;        // this lane's j (gate/c/h phase)

    __shared__ __align__(16) _Float16 hs2[2][16][136];  // padded: stride 136

    // ---- B-frags: wf[G][kc] = Whh[n = G*128 + j][kc*32 + qg*8 .. +8) as f16 ----
    f16x8 wf[4][4];
#pragma unroll
    for (int G = 0; G < 4; ++G)
#pragma unroll
        for (int kc = 0; kc < 4; ++kc) {
            const float* p = w_hh_l + (size_t)(d * G4 + G * HH + j) * HH + kc * 32 + qg * 8;
            float4 f0 = *(const float4*)p;
            float4 f1 = *(const float4*)(p + 4);
            wf[G][kc] = f16x8{(_Float16)f0.x, (_Float16)f0.y, (_Float16)f0.z, (_Float16)f0.w,
                              (_Float16)f1.x, (_Float16)f1.y, (_Float16)f1.z, (_Float16)f1.w};
        }

    // zero both h buffers
    for (int i = tid; i < 2 * 16 * 136; i += 512) ((_Float16*)hs2)[i] = (_Float16)0.f;
    __syncthreads();

    f32x4 c = {0.f, 0.f, 0.f, 0.f};
    const float* xp = xproj + (size_t)d * 1024 * 512 * 32;
    const int dt = d ? -1 : 1;
    const int t0 = d ? (TT - 1) : 0;
    const int xoff = hb * 16 + qg * 4;

    // prefetch x for step 0
    float4 xc[4];
#pragma unroll
    for (int G = 0; G < 4; ++G)
        xc[G] = *(const float4*)(xp + ((size_t)t0 * 512 + G * HH + j) * 32 + xoff);

    for (int step = 0; step < TT; ++step) {
        const int t = t0 + dt * step;
        const int cur = step & 1, nxt = cur ^ 1;

        bar_lgkm();   // h_{t-1} writes visible; x loads/out stores not drained

        // A-frags: H[b = col][k = kc*32 + qg*8 .. +8) from LDS (conflict-free b128)
        f16x8 af[4];
#pragma unroll
        for (int kc = 0; kc < 4; ++kc)
            af[kc] = *(const f16x8*)&hs2[cur][col][kc * 32 + qg * 8];

        // prefetch x for step+1 (in flight through the MFMA block)
        float4 xn[4];
        if (step + 1 < TT) {
            const int tn = t + dt;
#pragma unroll
            for (int G = 0; G < 4; ++G)
                xn[G] = *(const float4*)(xp + ((size_t)tn * 512 + G * HH + j) * 32 + xoff);
        }

        // gates(16 batches x 16 j) per gate G, K=128 over 4 chained MFMAs
        f32x4 ac[4];
#pragma unroll
        for (int G = 0; G < 4; ++G) {
            f32x4 a = {0.f, 0.f, 0.f, 0.f};
#pragma unroll
            for (int kc = 0; kc < 4; ++kc)
                a = __builtin_amdgcn_mfma_f32_16x16x32_f16(af[kc], wf[G][kc], a, 0, 0, 0);
            ac[G] = a;
        }

        // c/h update per reg r (batch b_loc = qg*4 + r), all in-register
        const float* x0 = (const float*)&xc[0];
        const float* x1 = (const float*)&xc[1];
        const float* x2 = (const float*)&xc[2];
        const float* x3 = (const float*)&xc[3];
#pragma unroll
        for (int r = 0; r < 4; ++r) {
            const float gi = rcpf(1.f + __expf(-(ac[0][r] + x0[r])));
            const float gf = rcpf(1.f + __expf(-(ac[1][r] + x1[r])));
            const float gg = 1.f - 2.f * rcpf(1.f + __expf(2.f * (ac[2][r] + x2[r])));
            const float go = rcpf(1.f + __expf(-(ac[3][r] + x3[r])));
            c[r] = gf * c[r] + gi * gg;
            const float th = 1.f - 2.f * rcpf(1.f + __expf(2.f * c[r]));
            const float h = go * th;
            hs2[nxt][qg * 4 + r][j] = (_Float16)h;
            const size_t bg = hb * 16 + qg * 4 + r;
            out[bg * (size_t)(TT * 256) + (size_t)t * 256 + d * HH + j] = h;
        }

        xc[0] = xn[0]; xc[1] = xn[1]; xc[2] = xn[2]; xc[3] = xn[3];
    }
}

// =============== Attention (last-row only) + FC ===============
__global__ __launch_bounds__(256) void attn_kernel(
    const float* __restrict__ out1,  // B x T x 256
    const float* __restrict__ wq, const float* __restrict__ bq,
    const float* __restrict__ wk,
    const float* __restrict__ wv, const float* __restrict__ bv,
    const float* __restrict__ wfc, const float* __restrict__ bfc,
    float* __restrict__ outp)        // B x 4
{
    const int b = blockIdx.x;
    const int tid = threadIdx.x;
    __shared__ float xl[256], q[256], u[256], cx[256];
    __shared__ __align__(16) float r[256];
    __shared__ float sc[TT];
    __shared__ float red[256];

    const float* ob = out1 + (size_t)b * TT * 256;

    xl[tid] = ob[(size_t)(TT - 1) * 256 + tid];
    __syncthreads();

    float acc = bq[tid];
    const float* wqr = wq + (size_t)tid * 256;
#pragma unroll 4
    for (int k = 0; k < 256; ++k) acc += xl[k] * wqr[k];
    q[tid] = acc;
    __syncthreads();

    acc = 0.f;
#pragma unroll 4
    for (int dd = 0; dd < 256; ++dd) acc += q[dd] * wk[(size_t)dd * 256 + tid];
    r[tid] = acc;
    __syncthreads();

    const int wave = tid >> 6, lane = tid & 63;
    float4 r4 = *(const float4*)&r[lane * 4];
    for (int t = wave; t < TT; t += 4) {
        float4 o4 = *(const float4*)(ob + (size_t)t * 256 + lane * 4);
        float p = r4.x * o4.x + r4.y * o4.y + r4.z * o4.z + r4.w * o4.w;
#pragma unroll
        for (int off = 32; off > 0; off >>= 1) p += __shfl_down(p, off, 64);
        if (lane == 0) sc[t] = p * 0.0625f;
    }
    __syncthreads();

    float mx = -1e30f;
#pragma unroll
    for (int i = 0; i < 4; ++i) mx = fmaxf(mx, sc[tid + 256 * i]);
    red[tid] = mx; __syncthreads();
    for (int st = 128; st > 0; st >>= 1) {
        if (tid < st) red[tid] = fmaxf(red[tid], red[tid + st]);
        __syncthreads();
    }
    mx = red[0]; __syncthreads();
    float lsum = 0.f;
#pragma unroll
    for (int i = 0; i < 4; ++i) {
        float e = expf(sc[tid + 256 * i] - mx);
        sc[tid + 256 * i] = e;
        lsum += e;
    }
    __syncthreads();
    red[tid] = lsum; __syncthreads();
    for (int st = 128; st > 0; st >>= 1) {
        if (tid < st) red[tid] += red[tid + st];
        __syncthreads();
    }
    const float inv = 1.f / red[0];
    __syncthreads();

    acc = 0.f;
#pragma unroll 8
    for (int t = 0; t < TT; ++t) acc += sc[t] * ob[(size_t)t * 256 + tid];
    u[tid] = acc * inv;
    __syncthreads();

    acc = bv[tid];
#pragma unroll 4
    for (int k = 0; k < 256; ++k) acc += u[k] * wv[(size_t)tid * 256 + k];
    cx[tid] = acc;
    __syncthreads();

    if (tid < 4) {
        float o = bfc[tid];
        for (int k = 0; k < 256; ++k) o += cx[k] * wfc[tid * 256 + k];
        outp[b * 4 + tid] = o;
    }
}

extern "C" void kernel_launch(void* const* d_in, const int* in_sizes, int n_in,
                              void* d_out, int out_size, void* d_ws, size_t ws_size,
                              hipStream_t stream)
{
    const float* x    = (const float*)d_in[0];
    const float* w_ih = (const float*)d_in[1];
    const float* w_hh = (const float*)d_in[2];
    const float* b_ih = (const float*)d_in[3];
    const float* b_hh = (const float*)d_in[4];
    const float* wq   = (const float*)d_in[5];
    const float* wk   = (const float*)d_in[6];
    const float* wv   = (const float*)d_in[7];
    const float* bq   = (const float*)d_in[8];
    const float* bv   = (const float*)d_in[10];
    const float* wfc  = (const float*)d_in[11];
    const float* bfcv = (const float*)d_in[12];
    float* outp = (float*)d_out;

    float* ws    = (float*)d_ws;
    float* xproj = ws;                        // 2*1024*512*32 floats (128 MB)
    float* out0  = ws + 33554432;             // 8,388,608 floats (32 MB)
    float* out1  = out0 + 8388608;            // 8,388,608 floats (32 MB)

    dim3 gg(4, 256, 2);   // 128x128 tiles over M=32768 (t-major), N=512

    gemm_inproj<<<gg, 256, 0, stream>>>(x, w_ih, b_ih, b_hh, xproj);
    lstm_rec<<<4, 512, 0, stream>>>(xproj, w_hh, out0);
    gemm_inproj<<<gg, 256, 0, stream>>>(out0, w_ih + 2 * 512 * 256, b_ih + 1024, b_hh + 1024, xproj);
    lstm_rec<<<4, 512, 0, stream>>>(xproj, w_hh + 2 * 512 * 128, out1);
    attn_kernel<<<32, 256, 0, stream>>>(out1, wq, bq, wk, wv, bv, wfc, bfcv, outp);
}

// Round 11
// 2743.643 us; speedup vs baseline: 1.2211x; 1.2211x over previous
//
#include <hip/hip_runtime.h>
#include <math.h>
#include <stdint.h>

#define BB 32
#define TT 1024
#define INF 256
#define HH 128
#define G4 512   // 4*H

typedef _Float16 half2_t __attribute__((ext_vector_type(2)));
typedef _Float16 f16x8 __attribute__((ext_vector_type(8)));
typedef float f32x4 __attribute__((ext_vector_type(4)));

__device__ __forceinline__ float fdot2f(half2_t a, half2_t b, float c) {
    return __builtin_amdgcn_fdot2(a, b, c, false);
}
__device__ __forceinline__ float rcpf(float x) {
    return __builtin_amdgcn_rcpf(x);
}
// workgroup barrier draining ONLY lgkmcnt — global loads/stores stay in flight
__device__ __forceinline__ void bar_lgkm() {
    asm volatile("s_waitcnt lgkmcnt(0)\n\ts_barrier" ::: "memory");
}

// =============== GEMM: f16 dot2, 128x128 tile; line-covered epilogue ===============
// Row index m = t*32 + b (t-major). Output layout xproj[d][t][8 bq][512 n][4 b]:
// each lane writes full 16-B float4s covering whole 64-B lines -> no RMW.
__global__ __launch_bounds__(256, 2) void gemm_inproj(
    const float* __restrict__ A,        // [32][1024][INF]  (b-major rows)
    const float* __restrict__ w_ih_l,   // 2 x 512 x INF  (this layer's slice)
    const float* __restrict__ b_ih_l,   // 2 x 512
    const float* __restrict__ b_hh_l,   // 2 x 512
    float* __restrict__ xproj)          // [2][1024][8][512][4]
{
    const int d  = blockIdx.z;
    const float* W = w_ih_l + (size_t)d * G4 * INF;
    float* C = xproj + (size_t)d * 1024 * 512 * 32;
    const int m0 = blockIdx.y * 128;    // t-major row base (multiple of 128)
    const int n0 = blockIdx.x * 128;
    const int tid = threadIdx.x;
    const int tx = tid & 15, ty = tid >> 4;

    __shared__ __align__(16) half2_t As2[16 * 128];   // 8 KB
    __shared__ __align__(16) half2_t Bs2[16 * 128];   // 8 KB

    float acc[8][8] = {};
    const int lr = tid >> 1;         // 0..127 : row for staging
    const int lk = (tid & 1) * 16;   // k offset for staging (16 floats/thread)

    const int mrow = m0 + lr;        // t-major index
    const size_t arow = ((size_t)(mrow & 31) * 1024 + (size_t)(mrow >> 5)) * INF;

    float4 ar4[4], br4[4];
#pragma unroll
    for (int i = 0; i < 4; ++i) {
        ar4[i] = *(const float4*)(A + arow + lk + 4 * i);
        br4[i] = *(const float4*)(W + (size_t)(n0 + lr) * INF + lk + 4 * i);
    }

    for (int k0 = 0; k0 < 256; k0 += 32) {
        __syncthreads();
#pragma unroll
        for (int i = 0; i < 4; ++i) {
            const int kp = (lk >> 1) + 2 * i;   // k-pair index
            As2[(kp + 0) * 128 + lr] = half2_t{(_Float16)ar4[i].x, (_Float16)ar4[i].y};
            As2[(kp + 1) * 128 + lr] = half2_t{(_Float16)ar4[i].z, (_Float16)ar4[i].w};
            Bs2[(kp + 0) * 128 + lr] = half2_t{(_Float16)br4[i].x, (_Float16)br4[i].y};
            Bs2[(kp + 1) * 128 + lr] = half2_t{(_Float16)br4[i].z, (_Float16)br4[i].w};
        }
        __syncthreads();
        if (k0 + 32 < 256) {
#pragma unroll
            for (int i = 0; i < 4; ++i) {
                ar4[i] = *(const float4*)(A + arow + k0 + 32 + lk + 4 * i);
                br4[i] = *(const float4*)(W + (size_t)(n0 + lr) * INF + k0 + 32 + lk + 4 * i);
            }
        }
#pragma unroll
        for (int kp = 0; kp < 16; ++kp) {
            half2_t av[8], bv[8];
            *(float4*)&av[0] = *(const float4*)&As2[kp * 128 + ty * 4];
            *(float4*)&av[4] = *(const float4*)&As2[kp * 128 + 64 + ty * 4];
            *(float4*)&bv[0] = *(const float4*)&Bs2[kp * 128 + tx * 4];
            *(float4*)&bv[4] = *(const float4*)&Bs2[kp * 128 + 64 + tx * 4];
#pragma unroll
            for (int i = 0; i < 8; ++i)
#pragma unroll
                for (int j = 0; j < 8; ++j)
                    acc[i][j] = fdot2f(av[i], bv[j], acc[i][j]);
        }
    }

    float bias[8];
#pragma unroll
    for (int j = 0; j < 8; ++j) {
        const int n = n0 + (j < 4 ? tx * 4 + j : 64 + tx * 4 + (j - 4));
        bias[j] = b_ih_l[d * G4 + n] + b_hh_l[d * G4 + n];
    }
#pragma unroll
    for (int q = 0; q < 2; ++q) {
        const int rbase = q * 64 + ty * 4;
        const int t  = (m0 >> 5) + (rbase >> 5);
        const int bq = (rbase & 31) >> 2;     // 0..7
        float* Cl = C + ((size_t)t * 8 + bq) * 512 * 4;
#pragma unroll
        for (int j = 0; j < 8; ++j) {
            const int n = n0 + (j < 4 ? tx * 4 + j : 64 + tx * 4 + (j - 4));
            float4 v;
            v.x = acc[q * 4 + 0][j] + bias[j];
            v.y = acc[q * 4 + 1][j] + bias[j];
            v.z = acc[q * 4 + 2][j] + bias[j];
            v.w = acc[q * 4 + 3][j] + bias[j];
            *(float4*)(Cl + (size_t)n * 4) = v;
        }
    }
}

// =============== LSTM recurrence: MFMA, 4-step x pipeline ===============
// Block = (direction d, batch-half hb): 16 chains; 8 waves, wave w owns
// gates i,f,g,o for j in [16w,16w+16).
// x loads issued at step s for step s+4 (unroll-4 -> compile-time parity):
// ~4 steps of latency cover, no vmcnt wait on the critical path.
// gates(16x512) = H(16x128) @ Whh^T via mfma_f32_16x16x32_f16; c/h update
// fully in-register (C-layout row == batch == reg index).
__global__ __launch_bounds__(512, 1) void lstm_rec(
    const float* __restrict__ xproj,   // [2][1024][8][512][4]
    const float* __restrict__ w_hh_l,  // 2 x 512 x 128 (this layer's slice)
    float* __restrict__ out)           // B x T x 256  ([fwd|bwd] concat)
{
    const int d  = blockIdx.x >> 1;
    const int hb = blockIdx.x & 1;
    const int tid = threadIdx.x;
    const int w = tid >> 6;
    const int l = tid & 63;
    const int col = l & 15;
    const int qg = l >> 4;
    const int j = w * 16 + col;        // this lane's j

    // stride 136 f16 = 272 B: multiple of 16 B (b128-aligned rows); col/col+8
    // 2-way bank aliasing is free.
    __shared__ __align__(16) _Float16 hs2[2][16][136];

    // ---- B-frags: wf[G][kc] = Whh[n = G*128 + j][kc*32 + qg*8 .. +8) as f16 ----
    f16x8 wf[4][4];
#pragma unroll
    for (int G = 0; G < 4; ++G)
#pragma unroll
        for (int kc = 0; kc < 4; ++kc) {
            const float* p = w_hh_l + (size_t)(d * G4 + G * HH + j) * HH + kc * 32 + qg * 8;
            float4 f0 = *(const float4*)p;
            float4 f1 = *(const float4*)(p + 4);
            wf[G][kc] = f16x8{(_Float16)f0.x, (_Float16)f0.y, (_Float16)f0.z, (_Float16)f0.w,
                              (_Float16)f1.x, (_Float16)f1.y, (_Float16)f1.z, (_Float16)f1.w};
        }

    for (int i = tid; i < 2 * 16 * 136; i += 512) ((_Float16*)hs2)[i] = (_Float16)0.f;
    __syncthreads();

    f32x4 c = {0.f, 0.f, 0.f, 0.f};
    const int dt = d ? -1 : 1;
    const int t0 = d ? (TT - 1) : 0;
    const int xrow = hb * 4 + qg;      // bq index in xproj

    // lane-fixed base: address(t, G) = xp + t*16384 + G*512  (floats)
    const float* xp = xproj + (size_t)d * 16777216 + (size_t)(xrow * 512 + j) * 4;

    // out pointers per r (batch hb*16+qg*4+r), advanced by dt*256 per step
    float* op[4];
#pragma unroll
    for (int r = 0; r < 4; ++r)
        op[r] = out + (size_t)(hb * 16 + qg * 4 + r) * (TT * 256) + (size_t)t0 * 256 + d * HH + j;

    // preload x for steps 0..3 (4-deep register pipeline)
    float4 xr[4][4];
#pragma unroll
    for (int pp = 0; pp < 4; ++pp) {
        const size_t toff = (size_t)(t0 + dt * pp) * 16384;
#pragma unroll
        for (int G = 0; G < 4; ++G)
            xr[pp][G] = *(const float4*)(xp + toff + G * 512);
    }

#pragma unroll 4
    for (int step = 0; step < TT; ++step) {
        const int cur = step & 3;          // x pipeline slot (compile-time)
        const int hc = step & 1, hn = hc ^ 1;  // h double-buffer parity

        bar_lgkm();   // h_{t-1} writes visible; in-flight x loads NOT drained

        // A-frags: H[b = col][k = kc*32 + qg*8 .. +8) from LDS
        f16x8 af[4];
#pragma unroll
        for (int kc = 0; kc < 4; ++kc)
            af[kc] = *(const f16x8*)&hs2[hc][col][kc * 32 + qg * 8];

        // gates: K=128 as two 2-deep MFMA chains + add
        f32x4 ac[4];
#pragma unroll
        for (int G = 0; G < 4; ++G) {
            f32x4 u = {0.f, 0.f, 0.f, 0.f};
            f32x4 v = {0.f, 0.f, 0.f, 0.f};
            u = __builtin_amdgcn_mfma_f32_16x16x32_f16(af[0], wf[G][0], u, 0, 0, 0);
            v = __builtin_amdgcn_mfma_f32_16x16x32_f16(af[1], wf[G][1], v, 0, 0, 0);
            u = __builtin_amdgcn_mfma_f32_16x16x32_f16(af[2], wf[G][2], u, 0, 0, 0);
            v = __builtin_amdgcn_mfma_f32_16x16x32_f16(af[3], wf[G][3], v, 0, 0, 0);
            ac[G] = u + v;
        }

        // c/h update per reg r (batch qg*4+r), in-register
        const float* x0 = (const float*)&xr[cur][0];
        const float* x1 = (const float*)&xr[cur][1];
        const float* x2 = (const float*)&xr[cur][2];
        const float* x3 = (const float*)&xr[cur][3];
#pragma unroll
        for (int r = 0; r < 4; ++r) {
            const float gi = rcpf(1.f + __expf(-(ac[0][r] + x0[r])));
            const float gf = rcpf(1.f + __expf(-(ac[1][r] + x1[r])));
            const float gg = 1.f - 2.f * rcpf(1.f + __expf(2.f * (ac[2][r] + x2[r])));
            const float go = rcpf(1.f + __expf(-(ac[3][r] + x3[r])));
            c[r] = gf * c[r] + gi * gg;
            const float th = 1.f - 2.f * rcpf(1.f + __expf(2.f * c[r]));
            const float h = go * th;
            hs2[hn][qg * 4 + r][j] = (_Float16)h;
            *op[r] = h;
            op[r] += dt * 256;
        }

        // prefetch x for step+4 into the slot just consumed
        if (step + 4 < TT) {
            const size_t toff = (size_t)(t0 + dt * (step + 4)) * 16384;
#pragma unroll
            for (int G = 0; G < 4; ++G)
                xr[cur][G] = *(const float4*)(xp + toff + G * 512);
        }
    }
}

// =============== Attention (last-row only) + FC ===============
__global__ __launch_bounds__(256) void attn_kernel(
    const float* __restrict__ out1,  // B x T x 256
    const float* __restrict__ wq, const float* __restrict__ bq,
    const float* __restrict__ wk,
    const float* __restrict__ wv, const float* __restrict__ bv,
    const float* __restrict__ wfc, const float* __restrict__ bfc,
    float* __restrict__ outp)        // B x 4
{
    const int b = blockIdx.x;
    const int tid = threadIdx.x;
    __shared__ float xl[256], q[256], u[256], cx[256];
    __shared__ __align__(16) float r[256];
    __shared__ float sc[TT];
    __shared__ float red[256];

    const float* ob = out1 + (size_t)b * TT * 256;

    xl[tid] = ob[(size_t)(TT - 1) * 256 + tid];
    __syncthreads();

    float acc = bq[tid];
    const float* wqr = wq + (size_t)tid * 256;
#pragma unroll 4
    for (int k = 0; k < 256; ++k) acc += xl[k] * wqr[k];
    q[tid] = acc;
    __syncthreads();

    acc = 0.f;
#pragma unroll 4
    for (int dd = 0; dd < 256; ++dd) acc += q[dd] * wk[(size_t)dd * 256 + tid];
    r[tid] = acc;
    __syncthreads();

    const int wave = tid >> 6, lane = tid & 63;
    float4 r4 = *(const float4*)&r[lane * 4];
    for (int t = wave; t < TT; t += 4) {
        float4 o4 = *(const float4*)(ob + (size_t)t * 256 + lane * 4);
        float p = r4.x * o4.x + r4.y * o4.y + r4.z * o4.z + r4.w * o4.w;
#pragma unroll
        for (int off = 32; off > 0; off >>= 1) p += __shfl_down(p, off, 64);
        if (lane == 0) sc[t] = p * 0.0625f;
    }
    __syncthreads();

    float mx = -1e30f;
#pragma unroll
    for (int i = 0; i < 4; ++i) mx = fmaxf(mx, sc[tid + 256 * i]);
    red[tid] = mx; __syncthreads();
    for (int st = 128; st > 0; st >>= 1) {
        if (tid < st) red[tid] = fmaxf(red[tid], red[tid + st]);
        __syncthreads();
    }
    mx = red[0]; __syncthreads();
    float lsum = 0.f;
#pragma unroll
    for (int i = 0; i < 4; ++i) {
        float e = expf(sc[tid + 256 * i] - mx);
        sc[tid + 256 * i] = e;
        lsum += e;
    }
    __syncthreads();
    red[tid] = lsum; __syncthreads();
    for (int st = 128; st > 0; st >>= 1) {
        if (tid < st) red[tid] += red[tid + st];
        __syncthreads();
    }
    const float inv = 1.f / red[0];
    __syncthreads();

    acc = 0.f;
#pragma unroll 8
    for (int t = 0; t < TT; ++t) acc += sc[t] * ob[(size_t)t * 256 + tid];
    u[tid] = acc * inv;
    __syncthreads();

    acc = bv[tid];
#pragma unroll 4
    for (int k = 0; k < 256; ++k) acc += u[k] * wv[(size_t)tid * 256 + k];
    cx[tid] = acc;
    __syncthreads();

    if (tid < 4) {
        float o = bfc[tid];
        for (int k = 0; k < 256; ++k) o += cx[k] * wfc[tid * 256 + k];
        outp[b * 4 + tid] = o;
    }
}

extern "C" void kernel_launch(void* const* d_in, const int* in_sizes, int n_in,
                              void* d_out, int out_size, void* d_ws, size_t ws_size,
                              hipStream_t stream)
{
    const float* x    = (const float*)d_in[0];
    const float* w_ih = (const float*)d_in[1];
    const float* w_hh = (const float*)d_in[2];
    const float* b_ih = (const float*)d_in[3];
    const float* b_hh = (const float*)d_in[4];
    const float* wq   = (const float*)d_in[5];
    const float* wk   = (const float*)d_in[6];
    const float* wv   = (const float*)d_in[7];
    const float* bq   = (const float*)d_in[8];
    const float* bv   = (const float*)d_in[10];
    const float* wfc  = (const float*)d_in[11];
    const float* bfcv = (const float*)d_in[12];
    float* outp = (float*)d_out;

    float* ws    = (float*)d_ws;
    float* xproj = ws;                        // 2*1024*8*512*4 floats (128 MB)
    float* out0  = ws + 33554432;             // 8,388,608 floats (32 MB)
    float* out1  = out0 + 8388608;            // 8,388,608 floats (32 MB)

    dim3 gg(4, 256, 2);   // 128x128 tiles over M=32768 (t-major), N=512

    gemm_inproj<<<gg, 256, 0, stream>>>(x, w_ih, b_ih, b_hh, xproj);
    lstm_rec<<<4, 512, 0, stream>>>(xproj, w_hh, out0);
    gemm_inproj<<<gg, 256, 0, stream>>>(out0, w_ih + 2 * 512 * 256, b_ih + 1024, b_hh + 1024, xproj);
    lstm_rec<<<4, 512, 0, stream>>>(xproj, w_hh + 2 * 512 * 128, out1);
    attn_kernel<<<32, 256, 0, stream>>>(out1, wq, bq, wk, wv, bv, wfc, bfcv, outp);
}

// Round 12
// 2685.566 us; speedup vs baseline: 1.2475x; 1.0216x over previous
//
#include <hip/hip_runtime.h>
#include <math.h>
#include <stdint.h>

#define BB 32
#define TT 1024
#define INF 256
#define HH 128
#define G4 512   // 4*H

typedef _Float16 half2_t __attribute__((ext_vector_type(2)));
typedef _Float16 f16x4 __attribute__((ext_vector_type(4)));
typedef _Float16 f16x8 __attribute__((ext_vector_type(8)));
typedef float f32x4 __attribute__((ext_vector_type(4)));

__device__ __forceinline__ float fdot2f(half2_t a, half2_t b, float c) {
    return __builtin_amdgcn_fdot2(a, b, c, false);
}
__device__ __forceinline__ float rcpf(float x) {
    return __builtin_amdgcn_rcpf(x);
}
// workgroup barrier draining ONLY lgkmcnt — global loads/stores stay in flight
__device__ __forceinline__ void bar_lgkm() {
    asm volatile("s_waitcnt lgkmcnt(0)\n\ts_barrier" ::: "memory");
}

// =============== GEMM: f16 dot2, 128x128 tile; f16 output ===============
// Row index m = t*32 + b (t-major). Output xproj[d][t][8 bq][512 n][4 b] in f16:
// halves lstm-side x bytes (the r11 bottleneck was per-CU x streaming).
__global__ __launch_bounds__(256, 2) void gemm_inproj(
    const float* __restrict__ A,        // [32][1024][INF]  (b-major rows)
    const float* __restrict__ w_ih_l,   // 2 x 512 x INF  (this layer's slice)
    const float* __restrict__ b_ih_l,   // 2 x 512
    const float* __restrict__ b_hh_l,   // 2 x 512
    _Float16* __restrict__ xproj)       // [2][1024][8][512][4] f16
{
    const int d  = blockIdx.z;
    const float* W = w_ih_l + (size_t)d * G4 * INF;
    _Float16* C = xproj + (size_t)d * 1024 * 512 * 32;
    const int m0 = blockIdx.y * 128;    // t-major row base
    const int n0 = blockIdx.x * 128;
    const int tid = threadIdx.x;
    const int tx = tid & 15, ty = tid >> 4;

    __shared__ __align__(16) half2_t As2[16 * 128];   // 8 KB
    __shared__ __align__(16) half2_t Bs2[16 * 128];   // 8 KB

    float acc[8][8] = {};
    const int lr = tid >> 1;         // 0..127 : row for staging
    const int lk = (tid & 1) * 16;   // k offset for staging

    const int mrow = m0 + lr;        // t-major index
    const size_t arow = ((size_t)(mrow & 31) * 1024 + (size_t)(mrow >> 5)) * INF;

    float4 ar4[4], br4[4];
#pragma unroll
    for (int i = 0; i < 4; ++i) {
        ar4[i] = *(const float4*)(A + arow + lk + 4 * i);
        br4[i] = *(const float4*)(W + (size_t)(n0 + lr) * INF + lk + 4 * i);
    }

    for (int k0 = 0; k0 < 256; k0 += 32) {
        __syncthreads();
#pragma unroll
        for (int i = 0; i < 4; ++i) {
            const int kp = (lk >> 1) + 2 * i;   // k-pair index
            As2[(kp + 0) * 128 + lr] = half2_t{(_Float16)ar4[i].x, (_Float16)ar4[i].y};
            As2[(kp + 1) * 128 + lr] = half2_t{(_Float16)ar4[i].z, (_Float16)ar4[i].w};
            Bs2[(kp + 0) * 128 + lr] = half2_t{(_Float16)br4[i].x, (_Float16)br4[i].y};
            Bs2[(kp + 1) * 128 + lr] = half2_t{(_Float16)br4[i].z, (_Float16)br4[i].w};
        }
        __syncthreads();
        if (k0 + 32 < 256) {
#pragma unroll
            for (int i = 0; i < 4; ++i) {
                ar4[i] = *(const float4*)(A + arow + k0 + 32 + lk + 4 * i);
                br4[i] = *(const float4*)(W + (size_t)(n0 + lr) * INF + k0 + 32 + lk + 4 * i);
            }
        }
#pragma unroll
        for (int kp = 0; kp < 16; ++kp) {
            half2_t av[8], bv[8];
            *(float4*)&av[0] = *(const float4*)&As2[kp * 128 + ty * 4];
            *(float4*)&av[4] = *(const float4*)&As2[kp * 128 + 64 + ty * 4];
            *(float4*)&bv[0] = *(const float4*)&Bs2[kp * 128 + tx * 4];
            *(float4*)&bv[4] = *(const float4*)&Bs2[kp * 128 + 64 + tx * 4];
#pragma unroll
            for (int i = 0; i < 8; ++i)
#pragma unroll
                for (int j = 0; j < 8; ++j)
                    acc[i][j] = fdot2f(av[i], bv[j], acc[i][j]);
        }
    }

    float bias[8];
#pragma unroll
    for (int j = 0; j < 8; ++j) {
        const int n = n0 + (j < 4 ? tx * 4 + j : 64 + tx * 4 + (j - 4));
        bias[j] = b_ih_l[d * G4 + n] + b_hh_l[d * G4 + n];
    }
#pragma unroll
    for (int q = 0; q < 2; ++q) {
        const int rbase = q * 64 + ty * 4;
        const int t  = (m0 >> 5) + (rbase >> 5);
        const int bq = (rbase & 31) >> 2;     // 0..7
        _Float16* Cl = C + ((size_t)t * 8 + bq) * 512 * 4;
#pragma unroll
        for (int j = 0; j < 8; ++j) {
            const int n = n0 + (j < 4 ? tx * 4 + j : 64 + tx * 4 + (j - 4));
            f16x4 v;
            v[0] = (_Float16)(acc[q * 4 + 0][j] + bias[j]);
            v[1] = (_Float16)(acc[q * 4 + 1][j] + bias[j]);
            v[2] = (_Float16)(acc[q * 4 + 2][j] + bias[j]);
            v[3] = (_Float16)(acc[q * 4 + 3][j] + bias[j]);
            *(f16x4*)(Cl + (size_t)n * 4) = v;
        }
    }
}

// =============== LSTM recurrence v12: MFMA, 4 chains/block, 16 blocks ===============
// Block = (direction d, batch-group bg of 4 chains). 8 waves; wave w owns
// gates i,f,g,o for j in [16w,16w+16). MFMA M=16 is 1/4-used (C rows 4..15
// ignored; garbage A rows only affect ignored C rows) — MFMA is not the
// bottleneck, per-CU memory streaming was (r11: 40 KB/step/CU at ~16 B/cyc).
// Now x = 4 KB f16/step/block on 4x more CUs. qg==0 lanes own the 4 chains.
__global__ __launch_bounds__(512, 1) void lstm_rec(
    const _Float16* __restrict__ xproj,  // [2][1024][8][512][4] f16
    const float* __restrict__ w_hh_l,    // 2 x 512 x 128 (this layer's slice)
    float* __restrict__ out)             // B x T x 256  ([fwd|bwd] concat)
{
    const int d  = blockIdx.x >> 3;
    const int bg = blockIdx.x & 7;     // batch-group: chains bg*4 .. bg*4+3
    const int tid = threadIdx.x;
    const int w = tid >> 6;
    const int l = tid & 63;
    const int col = l & 15;
    const int qg = l >> 4;
    const int j = w * 16 + col;        // this lane's j

    // stride 136 f16 = 272 B (16-B aligned rows); only rows 0..3 carry state.
    __shared__ __align__(16) _Float16 hs2[2][16][136];

    // ---- B-frags: wf[G][kc] = Whh[n = G*128 + j][kc*32 + qg*8 .. +8) as f16 ----
    f16x8 wf[4][4];
#pragma unroll
    for (int G = 0; G < 4; ++G)
#pragma unroll
        for (int kc = 0; kc < 4; ++kc) {
            const float* p = w_hh_l + (size_t)(d * G4 + G * HH + j) * HH + kc * 32 + qg * 8;
            float4 f0 = *(const float4*)p;
            float4 f1 = *(const float4*)(p + 4);
            wf[G][kc] = f16x8{(_Float16)f0.x, (_Float16)f0.y, (_Float16)f0.z, (_Float16)f0.w,
                              (_Float16)f1.x, (_Float16)f1.y, (_Float16)f1.z, (_Float16)f1.w};
        }

    for (int i = tid; i < 2 * 16 * 136; i += 512) ((_Float16*)hs2)[i] = (_Float16)0.f;
    __syncthreads();

    f32x4 c = {0.f, 0.f, 0.f, 0.f};
    const int dt = d ? -1 : 1;
    const int t0 = d ? (TT - 1) : 0;

    // x address (halves): ((t*8+bg)*512 + G*128 + j) * 4
    const _Float16* xp = xproj + (size_t)d * (1024 * 512 * 32)
                       + ((size_t)bg * 512 + j) * 4;

    // out pointers per r (batch bg*4+r), advanced by dt*256 per step
    float* op[4];
#pragma unroll
    for (int r = 0; r < 4; ++r)
        op[r] = out + (size_t)(bg * 4 + r) * (TT * 256) + (size_t)t0 * 256 + d * HH + j;

    // 4-deep x register pipeline (qg==0 lanes only)
    f16x4 xh[4][4];
    if (qg == 0) {
#pragma unroll
        for (int pp = 0; pp < 4; ++pp) {
            const size_t toff = (size_t)(t0 + dt * pp) * 16384;
#pragma unroll
            for (int G = 0; G < 4; ++G)
                xh[pp][G] = *(const f16x4*)(xp + toff + G * 512);
        }
    }

#pragma unroll 4
    for (int step = 0; step < TT; ++step) {
        const int cur = step & 3;              // x pipeline slot (compile-time)
        const int hc = step & 1, hn = hc ^ 1;  // h double-buffer parity

        bar_lgkm();   // h_{t-1} writes visible; in-flight x loads NOT drained

        // A-frags: H[b = col][k = kc*32 + qg*8 .. +8) from LDS (rows >3 = junk, ok)
        f16x8 af[4];
#pragma unroll
        for (int kc = 0; kc < 4; ++kc)
            af[kc] = *(const f16x8*)&hs2[hc][col][kc * 32 + qg * 8];

        // gates: K=128 as two 2-deep MFMA chains + add
        f32x4 ac[4];
#pragma unroll
        for (int G = 0; G < 4; ++G) {
            f32x4 u = {0.f, 0.f, 0.f, 0.f};
            f32x4 v = {0.f, 0.f, 0.f, 0.f};
            u = __builtin_amdgcn_mfma_f32_16x16x32_f16(af[0], wf[G][0], u, 0, 0, 0);
            v = __builtin_amdgcn_mfma_f32_16x16x32_f16(af[1], wf[G][1], v, 0, 0, 0);
            u = __builtin_amdgcn_mfma_f32_16x16x32_f16(af[2], wf[G][2], u, 0, 0, 0);
            v = __builtin_amdgcn_mfma_f32_16x16x32_f16(af[3], wf[G][3], v, 0, 0, 0);
            ac[G] = u + v;
        }

        if (qg == 0) {
            // c/h update per reg r (batch bg*4+r), in-register
#pragma unroll
            for (int r = 0; r < 4; ++r) {
                const float gi = rcpf(1.f + __expf(-(ac[0][r] + (float)xh[cur][0][r])));
                const float gf = rcpf(1.f + __expf(-(ac[1][r] + (float)xh[cur][1][r])));
                const float gg = 1.f - 2.f * rcpf(1.f + __expf(2.f * (ac[2][r] + (float)xh[cur][2][r])));
                const float go = rcpf(1.f + __expf(-(ac[3][r] + (float)xh[cur][3][r])));
                c[r] = gf * c[r] + gi * gg;
                const float th = 1.f - 2.f * rcpf(1.f + __expf(2.f * c[r]));
                const float h = go * th;
                hs2[hn][r][j] = (_Float16)h;
                *op[r] = h;
                op[r] += dt * 256;
            }
            // prefetch x for step+4 into the slot just consumed
            if (step + 4 < TT) {
                const size_t toff = (size_t)(t0 + dt * (step + 4)) * 16384;
#pragma unroll
                for (int G = 0; G < 4; ++G)
                    xh[cur][G] = *(const f16x4*)(xp + toff + G * 512);
            }
        }
    }
}

// =============== Attention (last-row only) + FC ===============
__global__ __launch_bounds__(256) void attn_kernel(
    const float* __restrict__ out1,  // B x T x 256
    const float* __restrict__ wq, const float* __restrict__ bq,
    const float* __restrict__ wk,
    const float* __restrict__ wv, const float* __restrict__ bv,
    const float* __restrict__ wfc, const float* __restrict__ bfc,
    float* __restrict__ outp)        // B x 4
{
    const int b = blockIdx.x;
    const int tid = threadIdx.x;
    __shared__ float xl[256], q[256], u[256], cx[256];
    __shared__ __align__(16) float r[256];
    __shared__ float sc[TT];
    __shared__ float red[256];

    const float* ob = out1 + (size_t)b * TT * 256;

    xl[tid] = ob[(size_t)(TT - 1) * 256 + tid];
    __syncthreads();

    float acc = bq[tid];
    const float* wqr = wq + (size_t)tid * 256;
#pragma unroll 4
    for (int k = 0; k < 256; ++k) acc += xl[k] * wqr[k];
    q[tid] = acc;
    __syncthreads();

    acc = 0.f;
#pragma unroll 4
    for (int dd = 0; dd < 256; ++dd) acc += q[dd] * wk[(size_t)dd * 256 + tid];
    r[tid] = acc;
    __syncthreads();

    const int wave = tid >> 6, lane = tid & 63;
    float4 r4 = *(const float4*)&r[lane * 4];
    for (int t = wave; t < TT; t += 4) {
        float4 o4 = *(const float4*)(ob + (size_t)t * 256 + lane * 4);
        float p = r4.x * o4.x + r4.y * o4.y + r4.z * o4.z + r4.w * o4.w;
#pragma unroll
        for (int off = 32; off > 0; off >>= 1) p += __shfl_down(p, off, 64);
        if (lane == 0) sc[t] = p * 0.0625f;
    }
    __syncthreads();

    float mx = -1e30f;
#pragma unroll
    for (int i = 0; i < 4; ++i) mx = fmaxf(mx, sc[tid + 256 * i]);
    red[tid] = mx; __syncthreads();
    for (int st = 128; st > 0; st >>= 1) {
        if (tid < st) red[tid] = fmaxf(red[tid], red[tid + st]);
        __syncthreads();
    }
    mx = red[0]; __syncthreads();
    float lsum = 0.f;
#pragma unroll
    for (int i = 0; i < 4; ++i) {
        float e = expf(sc[tid + 256 * i] - mx);
        sc[tid + 256 * i] = e;
        lsum += e;
    }
    __syncthreads();
    red[tid] = lsum; __syncthreads();
    for (int st = 128; st > 0; st >>= 1) {
        if (tid < st) red[tid] += red[tid + st];
        __syncthreads();
    }
    const float inv = 1.f / red[0];
    __syncthreads();

    acc = 0.f;
#pragma unroll 8
    for (int t = 0; t < TT; ++t) acc += sc[t] * ob[(size_t)t * 256 + tid];
    u[tid] = acc * inv;
    __syncthreads();

    acc = bv[tid];
#pragma unroll 4
    for (int k = 0; k < 256; ++k) acc += u[k] * wv[(size_t)tid * 256 + k];
    cx[tid] = acc;
    __syncthreads();

    if (tid < 4) {
        float o = bfc[tid];
        for (int k = 0; k < 256; ++k) o += cx[k] * wfc[tid * 256 + k];
        outp[b * 4 + tid] = o;
    }
}

extern "C" void kernel_launch(void* const* d_in, const int* in_sizes, int n_in,
                              void* d_out, int out_size, void* d_ws, size_t ws_size,
                              hipStream_t stream)
{
    const float* x    = (const float*)d_in[0];
    const float* w_ih = (const float*)d_in[1];
    const float* w_hh = (const float*)d_in[2];
    const float* b_ih = (const float*)d_in[3];
    const float* b_hh = (const float*)d_in[4];
    const float* wq   = (const float*)d_in[5];
    const float* wk   = (const float*)d_in[6];
    const float* wv   = (const float*)d_in[7];
    const float* bq   = (const float*)d_in[8];
    const float* bv   = (const float*)d_in[10];
    const float* wfc  = (const float*)d_in[11];
    const float* bfcv = (const float*)d_in[12];
    float* outp = (float*)d_out;

    _Float16* xproj = (_Float16*)d_ws;                    // 2*1024*8*512*4 f16 = 64 MB
    float* out0 = (float*)((char*)d_ws + 67108864);       // 32 MB
    float* out1 = (float*)((char*)d_ws + 67108864 + 33554432);  // 32 MB

    dim3 gg(4, 256, 2);   // 128x128 tiles over M=32768 (t-major), N=512

    gemm_inproj<<<gg, 256, 0, stream>>>(x, w_ih, b_ih, b_hh, xproj);
    lstm_rec<<<16, 512, 0, stream>>>(xproj, w_hh, out0);
    gemm_inproj<<<gg, 256, 0, stream>>>(out0, w_ih + 2 * 512 * 256, b_ih + 1024, b_hh + 1024, xproj);
    lstm_rec<<<16, 512, 0, stream>>>(xproj, w_hh + 2 * 512 * 128, out1);
    attn_kernel<<<32, 256, 0, stream>>>(out1, wq, bq, wk, wv, bv, wfc, bfcv, outp);
}